// Round 5
// baseline (489.519 us; speedup 1.0000x reference)
//
#include <hip/hip_runtime.h>

#define SEQ 128
#define HID 32
#define TPB 128   // 2 waves, 16 nodes per block
#define XS 56     // LDS row stride in shorts: 112B = 7*16B -> 2-way-max bank pattern

typedef __attribute__((ext_vector_type(8))) short short8;   // 8 bf16 = 4 VGPR
typedef __attribute__((ext_vector_type(4))) short short4v;  // 4 shorts = 8B
typedef __attribute__((ext_vector_type(4))) float floatx4;  // MFMA acc

// ---------------- GCN prep ----------------

__global__ void count_kernel(const int* __restrict__ idx, int E, int* __restrict__ cnt) {
    int e = (blockIdx.x * blockDim.x + threadIdx.x) * 4;
    if (((E & 3) == 0) && e + 3 < E) {
        int4 d = *(const int4*)(idx + E + e);   // 16B aligned: E%4==0, e%4==0
        atomicAdd(&cnt[d.x], 1);
        atomicAdd(&cnt[d.y], 1);
        atomicAdd(&cnt[d.z], 1);
        atomicAdd(&cnt[d.w], 1);
    } else {
        int lim = min(e + 4, E);
        for (int k = e; k < lim; ++k) atomicAdd(&cnt[idx[E + k]], 1);
    }
}

// Fixed-point pack: q = rn(v * 2^21), biased +2^26 per 32b field. Every added term
// is positive and < 2^26.2 -> no carry between fields up to ~56 adds (max realistic
// deg ~12 for Poisson(0.78)). ONE u64 atomic per edge; dinv[src] computed inline
// from the deg gather (round-1 evidence: scatter is atomic-rate-bound, extra
// gather streams are free), so the dinv/xs pre-pass is deleted entirely.
__device__ __forceinline__ unsigned long long pk2(float xx, float yy, float dv) {
    int qx = __float2int_rn(xx * dv * 2097152.0f);
    int qy = __float2int_rn(yy * dv * 2097152.0f);
    return ((unsigned long long)(unsigned)(qx + (1 << 26)) << 32) |
           (unsigned)(qy + (1 << 26));
}

__global__ void scatter_pk_kernel(const int* __restrict__ idx, int E,
                                  const float2* __restrict__ x2,
                                  const int* __restrict__ deg,
                                  unsigned long long* __restrict__ aggP) {
    int e = (blockIdx.x * blockDim.x + threadIdx.x) * 4;
    if (((E & 3) == 0) && e + 3 < E) {
        int4 s = *(const int4*)(idx + e);
        int4 d = *(const int4*)(idx + E + e);
        float2 v0 = x2[s.x];
        float2 v1 = x2[s.y];
        float2 v2 = x2[s.z];
        float2 v3 = x2[s.w];
        float dv0 = rsqrtf((float)deg[s.x] + 1.0f);
        float dv1 = rsqrtf((float)deg[s.y] + 1.0f);
        float dv2 = rsqrtf((float)deg[s.z] + 1.0f);
        float dv3 = rsqrtf((float)deg[s.w] + 1.0f);
        atomicAdd(&aggP[d.x], pk2(v0.x, v0.y, dv0));
        atomicAdd(&aggP[d.y], pk2(v1.x, v1.y, dv1));
        atomicAdd(&aggP[d.z], pk2(v2.x, v2.y, dv2));
        atomicAdd(&aggP[d.w], pk2(v3.x, v3.y, dv3));
    } else {
        int lim = min(e + 4, E);
        for (int k = e; k < lim; ++k) {
            int s = idx[k];
            int d = idx[E + k];
            float2 v = x2[s];
            float dv = rsqrtf((float)deg[s] + 1.0f);
            atomicAdd(&aggP[d], pk2(v.x, v.y, dv));
        }
    }
}

// ---------------- MFMA LSTM, 2 waves / 16 nodes, register-xg ----------------
// Wave w owns gates i,f,g,o for units 8q+4w+r (row-permuted W tiles; layout
// HW-verified). KEY CHANGE vs r3: each lane computes xg for ALL 8 units of its
// own B-frag (units 8q..8q+7 of node l15) -- duplicated across waves, but xg
// then lives in REGISTERS: no xg LDS buffers, and the 12 x-term MFMAs for step
// t+1 (bias + AiH*xh + AiL*xh + AiH*xl, depth-3 chain) run DURING step t,
// since they depend only on ubuf. The barrier-protected critical path per step
// is now: ds_read(h) -> depth-3 h-MFMA chain -> activations -> h-write ->
// barrier (was depth-6 + 4 LDS reads + 4 writes). Only h crosses the wave
// boundary (hi/lo shorts, stride 112B: one ds_read_b128 at [l15*112+16q] IS
// the B-frag; 28*l15 mod 32 has period 8 -> free 2-way bank aliasing only).
// Single barrier per step; ping-pong h buffers with COMPILE-TIME parity.

__device__ __forceinline__ float sigm_f(float x) {
    return __builtin_amdgcn_rcpf(1.0f + __expf(-x));
}
__device__ __forceinline__ float tanh_f(float x) {
    return fmaf(__builtin_amdgcn_rcpf(1.0f + __expf(-2.0f * x)), 2.0f, -1.0f);
}
// truncation split: f = hi + lo (~2^-16 rel); 3-term MFMA keeps fp32-like precision
__device__ __forceinline__ void fsplit(float f, short& hi, short& lo) {
    unsigned u = __float_as_uint(f);
    hi = (short)(u >> 16);
    float r = f - __uint_as_float(u & 0xFFFF0000u);
    lo = (short)(__float_as_uint(r) >> 16);
}

__global__ __launch_bounds__(TPB, 2) void lstm_mfma4_kernel(
    const float2* __restrict__ x2,
    const unsigned long long* __restrict__ aggP, const int* __restrict__ deg,
    int N,
    const float* __restrict__ gcn_W, const float* __restrict__ gcn_b,
    const float* __restrict__ w_ih, const float* __restrict__ w_hh,
    const float* __restrict__ b_ih, const float* __restrict__ b_hh,
    const float* __restrict__ fc_W, const float* __restrict__ fc_b,
    float* __restrict__ out) {
    __shared__ float2 ubuf[16][SEQ + 1];                 // 16.5 KB (col 128 = zero pad)
    __shared__ __align__(16) short hhb[2][16][XS];       // h hi, ping-pong
    __shared__ __align__(16) short hlb[2][16][XS];       // h lo
    __shared__ float fcp[2][16];

    const int tid = threadIdx.x;
    const int w = tid >> 6;       // wave id = mtl
    const int lane = tid & 63;
    const int l15 = lane & 15;
    const int q = lane >> 4;
    const int base = blockIdx.x * 16;

    // ---- Phase A: stage u[node][t] = dv*(agg + x*dv) into LDS (coalesced) ----
    {
        const float2* xb = x2 + (size_t)base * SEQ;
        const unsigned long long* apb = aggP + (size_t)base * SEQ;
        const int* dgb = deg + (size_t)base * SEQ;
        const int lim = min(16 * SEQ, (N - base) * SEQ);
        for (int i = tid; i < 16 * SEQ; i += TPB) {
            float2 v = make_float2(0.f, 0.f);
            if (i < lim) {
                int dg = dgb[i];
                float dv = rsqrtf((float)dg + 1.0f);
                float2 xx = xb[i];
                unsigned long long pk = apb[i];
                unsigned bias = (unsigned)dg * 67108864u;  // deg * 2^26
                float ax = (float)((int)((unsigned)(pk >> 32) - bias)) * (1.0f / 2097152.0f);
                float ay = (float)((int)((unsigned)pk - bias)) * (1.0f / 2097152.0f);
                v = make_float2(dv * fmaf(xx.x, dv, ax), dv * fmaf(xx.y, dv, ay));
            }
            ubuf[i >> 7][i & 127] = v;
        }
        if (tid < 16) ubuf[tid][SEQ] = make_float2(0.f, 0.f);  // pad col (t=127 prefetch)
    }

    // ---- constant A-frags (4 tiles = gates i,f,g,o at mtl=w), hi/lo bf16 ----
    short8 AiH[4], AiL[4], AhH[4], AhL[4];
    floatx4 biasC[4];
    #pragma unroll
    for (int g = 0; g < 4; ++g) {
        const int arow = g * 32 + 8 * (l15 >> 2) + 4 * w + (l15 & 3);
        const float* wi = w_ih + arow * HID + 8 * q;
        const float* wh = w_hh + arow * HID + 8 * q;
        #pragma unroll
        for (int j = 0; j < 8; ++j) {
            short h16, l16;
            fsplit(wi[j], h16, l16); AiH[g][j] = h16; AiL[g][j] = l16;
            fsplit(wh[j], h16, l16); AhH[g][j] = h16; AhL[g][j] = l16;
        }
        #pragma unroll
        for (int r = 0; r < 4; ++r) {
            const int brow = g * 32 + 8 * q + 4 * w + r;
            biasC[g][r] = b_ih[brow] + b_hh[brow];
        }
    }

    // ---- GCN consts for ALL 8 B-frag units of this lane: u = 8q + j ----
    float wg0[8], wg1[8], gbc[8];
    #pragma unroll
    for (int j = 0; j < 8; ++j) {
        const int u = 8 * q + j;
        wg0[j] = gcn_W[u];
        wg1[j] = gcn_W[HID + u];
        gbc[j] = gcn_b[u];
    }
    float fcw[4];
    #pragma unroll
    for (int r = 0; r < 4; ++r) fcw[r] = fc_W[8 * q + 4 * w + r];  // own C-slots

    float c[4] = {0.f, 0.f, 0.f, 0.f};
    float ho[4] = {0.f, 0.f, 0.f, 0.f};

    __syncthreads();  // ubuf staged

// xg frags for time TT: this lane's full B-frag (units 8q..8q+7 of node l15)
#define XG_FRAGS(TT, XH, XL)                                                  \
    {                                                                         \
        float2 uu = ubuf[l15][TT];                                            \
        _Pragma("unroll") for (int j = 0; j < 8; ++j) {                       \
            float g = fmaxf(fmaf(uu.x, wg0[j], fmaf(uu.y, wg1[j], gbc[j])), 0.f); \
            short h16, l16;                                                   \
            fsplit(g, h16, l16);                                              \
            XH[j] = h16; XL[j] = l16;                                         \
        }                                                                     \
    }

    // ---- prologue: h(-1)=0 into buffer 0; xg(0) frags + x-term accs ----
    *(short4v*)&hhb[0][l15][8 * q + 4 * w] = (short4v){0, 0, 0, 0};
    *(short4v*)&hlb[0][l15][8 * q + 4 * w] = (short4v){0, 0, 0, 0};
    short8 xhA, xlA, xhB, xlB;
    floatx4 aXA[4], aXB[4];
    XG_FRAGS(0, xhA, xlA);
    #pragma unroll
    for (int g = 0; g < 4; ++g)
        aXA[g] = __builtin_amdgcn_mfma_f32_16x16x32_bf16(AiH[g], xhA, biasC[g], 0, 0, 0);
    #pragma unroll
    for (int g = 0; g < 4; ++g)
        aXA[g] = __builtin_amdgcn_mfma_f32_16x16x32_bf16(AiL[g], xhA, aXA[g], 0, 0, 0);
    #pragma unroll
    for (int g = 0; g < 4; ++g)
        aXA[g] = __builtin_amdgcn_mfma_f32_16x16x32_bf16(AiH[g], xlA, aXA[g], 0, 0, 0);
    __syncthreads();

// One step, compile-time parity P: reads h from buf P, writes h to buf P^1.
// h-chain (depth 3) extends AXC (bias + x-terms, computed LAST step); next
// step's xg frags + x-term MFMAs (independent of the barrier) fill the pipe.
#define LSTM_STEP(P, TT, AXC, AXN, XHN, XLN)                                               \
    do {                                                                                   \
        const short8 hh = *(const short8*)&hhb[P][l15][8 * q];                             \
        const short8 hl = *(const short8*)&hlb[P][l15][8 * q];                             \
        floatx4 acc[4];                                                                    \
        __builtin_amdgcn_s_setprio(1);                                                     \
        _Pragma("unroll") for (int g = 0; g < 4; ++g)                                      \
            acc[g] = __builtin_amdgcn_mfma_f32_16x16x32_bf16(AhH[g], hh, AXC[g], 0, 0, 0); \
        _Pragma("unroll") for (int g = 0; g < 4; ++g)                                      \
            acc[g] = __builtin_amdgcn_mfma_f32_16x16x32_bf16(AhL[g], hh, acc[g], 0, 0, 0); \
        _Pragma("unroll") for (int g = 0; g < 4; ++g)                                      \
            acc[g] = __builtin_amdgcn_mfma_f32_16x16x32_bf16(AhH[g], hl, acc[g], 0, 0, 0); \
        __builtin_amdgcn_s_setprio(0);                                                     \
        XG_FRAGS((TT) + 1, XHN, XLN);                                                      \
        __builtin_amdgcn_s_setprio(1);                                                     \
        _Pragma("unroll") for (int g = 0; g < 4; ++g)                                      \
            AXN[g] = __builtin_amdgcn_mfma_f32_16x16x32_bf16(AiH[g], XHN, biasC[g], 0, 0, 0); \
        _Pragma("unroll") for (int g = 0; g < 4; ++g)                                      \
            AXN[g] = __builtin_amdgcn_mfma_f32_16x16x32_bf16(AiL[g], XHN, AXN[g], 0, 0, 0); \
        _Pragma("unroll") for (int g = 0; g < 4; ++g)                                      \
            AXN[g] = __builtin_amdgcn_mfma_f32_16x16x32_bf16(AiH[g], XLN, AXN[g], 0, 0, 0); \
        __builtin_amdgcn_s_setprio(0);                                                     \
        {                                                                                  \
            short hi[4], lo[4];                                                            \
            _Pragma("unroll") for (int r = 0; r < 4; ++r) {                                \
                const float ig = sigm_f(acc[0][r]);                                        \
                const float fg = sigm_f(acc[1][r]);                                        \
                const float gg = tanh_f(acc[2][r]);                                        \
                const float og = sigm_f(acc[3][r]);                                        \
                c[r] = fmaf(fg, c[r], ig * gg);                                            \
                const float hv = og * tanh_f(c[r]);                                        \
                ho[r] = hv;                                                                \
                fsplit(hv, hi[r], lo[r]);                                                  \
            }                                                                              \
            *(short4v*)&hhb[(P) ^ 1][l15][8 * q + 4 * w] =                                 \
                (short4v){hi[0], hi[1], hi[2], hi[3]};                                     \
            *(short4v*)&hlb[(P) ^ 1][l15][8 * q + 4 * w] =                                 \
                (short4v){lo[0], lo[1], lo[2], lo[3]};                                     \
        }                                                                                  \
        __syncthreads();                                                                   \
    } while (0)

    #pragma unroll 1
    for (int t = 0; t < SEQ; t += 2) {
        LSTM_STEP(0, t,     aXA, aXB, xhB, xlB);  // reads h buf 0, writes buf 1
        LSTM_STEP(1, t + 1, aXB, aXA, xhA, xlA);  // reads h buf 1, writes buf 0
    }
#undef LSTM_STEP
#undef XG_FRAGS

    // ---- FC epilogue ----
    float partial = fmaf(ho[0], fcw[0], fmaf(ho[1], fcw[1],
                    fmaf(ho[2], fcw[2], ho[3] * fcw[3])));
    partial += __shfl_xor(partial, 16);
    partial += __shfl_xor(partial, 32);
    if (lane < 16) fcp[w][l15] = partial;
    __syncthreads();
    if (w == 0 && lane < 16) {
        const int node = base + l15;
        if (node < N) out[node] = fcp[0][l15] + fcp[1][l15] + fc_b[0];
    }
}

extern "C" void kernel_launch(void* const* d_in, const int* in_sizes, int n_in,
                              void* d_out, int out_size, void* d_ws, size_t ws_size,
                              hipStream_t stream) {
    const float* x     = (const float*)d_in[0];
    const int*   idx   = (const int*)d_in[1];
    const float* gcn_W = (const float*)d_in[2];
    const float* gcn_b = (const float*)d_in[3];
    const float* w_ih  = (const float*)d_in[4];
    const float* w_hh  = (const float*)d_in[5];
    const float* b_ih  = (const float*)d_in[6];
    const float* b_hh  = (const float*)d_in[7];
    const float* fc_W  = (const float*)d_in[8];
    const float* fc_b  = (const float*)d_in[9];

    const int num_nodes = in_sizes[0] / (SEQ * 2);
    const int ntot = num_nodes * SEQ;
    const int E = in_sizes[1] / 2;

    // workspace: deg[ntot i32] | aggP[ntot u64]  (3 planes of 4B)
    int* deg = (int*)d_ws;
    unsigned long long* aggP = (unsigned long long*)((char*)d_ws + (size_t)ntot * 4);

    hipMemsetAsync(d_ws, 0, (size_t)ntot * 12, stream);

    const int eb = (E + 1023) / 1024;  // 4 edges/thread, 256 threads/block
    count_kernel<<<eb, 256, 0, stream>>>(idx, E, deg);
    scatter_pk_kernel<<<eb, 256, 0, stream>>>(idx, E, (const float2*)x, deg, aggP);
    lstm_mfma4_kernel<<<(num_nodes + 15) / 16, TPB, 0, stream>>>(
        (const float2*)x, aggP, deg, num_nodes,
        gcn_W, gcn_b, w_ih, w_hh, b_ih, b_hh, fc_W, fc_b,
        (float*)d_out);
}